// Round 1
// 147.367 us; speedup vs baseline: 1.0582x; 1.0582x over previous
//
#include <hip/hip_runtime.h>

// Normalized-Hermite per-dim prefactors: c_n = (2^n * n! * sqrt(pi))^{-1/2}
#define C0 0.7511255444649425f
#define C1 0.5311259660135985f
#define C2 0.2655629830067992f
#define C3 0.1084156342944575f

// One thread per site: computes all 16 orbitals once (no 4x redundancy, no
// cndmask select chain), stages the 64 B/site result through LDS to produce
// fully coalesced float4 global stores (identical store pattern to the
// previous kernel, 1/4 the waves and ~1/5 the VALU issue).
__global__ __launch_bounds__(256) void hermite_orbitals_kernel(
    const float* __restrict__ x, float* __restrict__ out, int nsites)
{
    __shared__ float4 sh[256 * 4];  // 16 KB: 256 sites x 4 quads (swizzled)

    const int t = threadIdx.x;
    const int s = blockIdx.x * 256 + t;

    // Clamp (never triggers for the fixed shape: 2,097,152 = 8192*256)
    const int sc = s < nsites ? s : nsites - 1;

    const float x0 = x[3 * sc + 0];
    const float x1 = x[3 * sc + 1];
    const float x2 = x[3 * sc + 2];

    const float t0 = x0 * x0, t1 = x1 * x1, t2 = x2 * x2;
    const float env = __expf(-0.5f * (t0 + t1 + t2));

    // Per-dim normalized Hermite factors: g_n = c_n * H_n(x)
    // H0=1, H1=2x, H2=4x^2-2, H3=4x(2x^2-3)
    const float Y1 = (2.0f * C1) * x1;
    const float Y2 = C2 * (4.0f * t1 - 2.0f);
    const float Y3 = (4.0f * C3) * x1 * (2.0f * t1 - 3.0f);

    const float Z1 = (2.0f * C1) * x2;
    const float Z2 = C2 * (4.0f * t2 - 2.0f);
    const float Z3 = (4.0f * C3) * x2 * (2.0f * t2 - 3.0f);

    // env-folded X factors
    const float e0 = env * C0;
    const float e1 = env * (2.0f * C1) * x0;
    const float e2 = env * C2 * (4.0f * t0 - 2.0f);
    const float e3 = env * (4.0f * C3) * x0 * (2.0f * t0 - 3.0f);

    // CSE groups w_ij = e_i * Y_j  (only the (i,j) pairs that occur)
    const float w00 = e0 * C0;
    const float w01 = e0 * Y1;
    const float w02 = e0 * Y2;
    const float w03 = e0 * Y3;
    const float w10 = e1 * C0;
    const float w11 = e1 * Y1;
    const float w20 = e2 * C0;

    // Orbital table (stable-sort-by-sum order of multi-indices, P=16):
    //  0:(0,0,0)  1:(0,0,1)  2:(0,1,0)  3:(1,0,0)
    //  4:(0,0,2)  5:(0,1,1)  6:(0,2,0)  7:(1,0,1)
    //  8:(1,1,0)  9:(2,0,0) 10:(0,0,3) 11:(0,1,2)
    // 12:(0,2,1) 13:(0,3,0) 14:(1,0,2) 15:(1,1,1)
    float4 r0, r1, r2v, r3;
    r0.x = w00 * C0;   // p0
    r0.y = w00 * Z1;   // p1
    r0.z = w01 * C0;   // p2
    r0.w = w10 * C0;   // p3

    r1.x = w00 * Z2;   // p4
    r1.y = w01 * Z1;   // p5
    r1.z = w02 * C0;   // p6
    r1.w = w10 * Z1;   // p7

    r2v.x = w11 * C0;  // p8
    r2v.y = w20 * C0;  // p9
    r2v.z = w00 * Z3;  // p10
    r2v.w = w01 * Z2;  // p11

    r3.x = w02 * Z1;   // p12
    r3.y = w03 * C0;   // p13
    r3.z = w10 * Z2;   // p14
    r3.w = w11 * Z1;   // p15

    // Swizzled LDS write: quad k of site t at slot (k+t)&3 (8-way max conflict)
    sh[(t << 2) + (((0 + t) & 3))] = r0;
    sh[(t << 2) + (((1 + t) & 3))] = r1;
    sh[(t << 2) + (((2 + t) & 3))] = r2v;
    sh[(t << 2) + (((3 + t) & 3))] = r3;

    __syncthreads();

    // Coalesced write-out: block's out region = 1024 contiguous float4
    float4* ob = reinterpret_cast<float4*>(out) + ((size_t)blockIdx.x << 10);
#pragma unroll
    for (int k = 0; k < 4; ++k) {
        const int j = t + (k << 8);   // float4 index in block region
        const int m = j >> 2;         // site within block
        const int q = j & 3;          // quad
        ob[j] = sh[(m << 2) + ((q + m) & 3)];
    }
}

extern "C" void kernel_launch(void* const* d_in, const int* in_sizes, int n_in,
                              void* d_out, int out_size, void* d_ws, size_t ws_size,
                              hipStream_t stream) {
    const float* x = (const float*)d_in[0];
    float* out = (float*)d_out;

    const int nsites = in_sizes[0] / 3;       // W * A = 2,097,152
    const int block = 256;
    const int grid = (nsites + block - 1) / block;

    hermite_orbitals_kernel<<<grid, block, 0, stream>>>(x, out, nsites);
}